// Round 6
// baseline (1760.987 us; speedup 1.0000x reference)
//
#include <hip/hip_runtime.h>

#define HDIM 1024
#define LLBS 1048576L   // 1024*1024 elements
#define OPTBS 262144L   // 256*1024 elements

typedef _Float16 f16;
typedef __attribute__((ext_vector_type(8))) _Float16 f16x8;
typedef __attribute__((ext_vector_type(4))) _Float16 f16x4;
typedef __attribute__((ext_vector_type(4))) float    f32x4;

// ==== swizzled LDS tile: [128 rows][64 f16] linear (16 KB), 16B XOR swizzle ====
// byte addr = row*128 + (colb ^ ((row&7)<<4))  — involution on 16B units.
__device__ __forceinline__ char* swzp(f16* tile, int row, int colb) {
  return (char*)tile + (row << 7) + (colb ^ ((row & 7) << 4));
}
__device__ __forceinline__ const char* swzp(const f16* tile, int row, int colb) {
  return (const char*)tile + (row << 7) + (colb ^ ((row & 7) << 4));
}

__device__ __forceinline__ void gload16(const f16* g, f16* l) {
  __builtin_amdgcn_global_load_lds((const __attribute__((address_space(1))) void*)g,
                                   (__attribute__((address_space(3))) void*)l, 16, 0, 0);
}

// stage 128x64 f16 tile via global_load_lds DMA; linear LDS dest, inverse-swizzled
// per-lane global source so that swizzled reads return the right data (rule 21).
__device__ __forceinline__
void stage_g(f16* __restrict__ tile, const f16* __restrict__ src, long rs, int t)
{
  const int l = t & 63, w = t >> 6;
  const int rsub = l >> 3;                    // row within 8-row stripe
  const int csub = ((l & 7) ^ rsub) << 3;     // pre-swizzled 16B column (f16 units)
  const f16* gp = src + (long)rsub * rs + csub;
  #pragma unroll
  for (int p = 0; p < 4; ++p) {
    const int i = (w << 2) + p;               // 0..15: 1KB LDS chunk index
    gload16(gp + (long)(i << 3) * rs, tile + (i << 9));
  }
}

// ---- reg-staged V-transpose (B rows are k): load part / write part split (T14) ----
struct VT { f16x4 r[8]; };
__device__ __forceinline__ VT vt_load(const f16* __restrict__ src, long rs, int t) {
  const int jc = (t & 31) << 2, kg = (t >> 5) << 3;
  const f16* p = src + (long)kg * rs + jc;
  VT v;
  #pragma unroll
  for (int e = 0; e < 8; ++e) v.r[e] = *(const f16x4*)(p + (long)e * rs);
  return v;
}
__device__ __forceinline__ void vt_write(f16* __restrict__ tile, const VT& v, int t) {
  const int jc = (t & 31) << 2, kg = (t >> 5) << 3;
  #pragma unroll
  for (int c = 0; c < 4; ++c)
    *(f16x8*)swzp(tile, jc + c, kg << 1) =
      f16x8{v.r[0][c], v.r[1][c], v.r[2][c], v.r[3][c],
            v.r[4][c], v.r[5][c], v.r[6][c], v.r[7][c]};
}

// ---- reg-staged row loads (row = t>>1, 32 f16 half-row each) ----
__device__ __forceinline__ void ld4(f16x8 v[4], const f16* p) {
  const f16x8* q = (const f16x8*)p;
  v[0] = q[0]; v[1] = q[1]; v[2] = q[2]; v[3] = q[3];
}
__device__ __forceinline__ void a_write(f16* __restrict__ tile, const f16x8 v[4], int t) {
  const int row = t >> 1, h2 = (t & 1) << 6;   // byte col base 0/64
  #pragma unroll
  for (int e = 0; e < 4; ++e)
    *(f16x8*)swzp(tile, row, h2 + (e << 4)) = v[e];
}
__device__ __forceinline__
void sc_load(f16x8 v[4], const f16* __restrict__ src, long rs,
             const float* __restrict__ sc, int t)
{
  const int row = t >> 1, h = (t & 1) << 5;
  ld4(v, src + (long)row * rs + h);
  #pragma unroll
  for (int e = 0; e < 4; ++e) {
    const float4 s0 = *(const float4*)(sc + h + e * 8);
    const float4 s1 = *(const float4*)(sc + h + e * 8 + 4);
    f16x8 x = v[e];
    x[0]=(f16)((float)x[0]*s0.x); x[1]=(f16)((float)x[1]*s0.y);
    x[2]=(f16)((float)x[2]*s0.z); x[3]=(f16)((float)x[3]*s0.w);
    x[4]=(f16)((float)x[4]*s1.x); x[5]=(f16)((float)x[5]*s1.y);
    x[6]=(f16)((float)x[6]*s1.z); x[7]=(f16)((float)x[7]*s1.w);
    v[e] = x;
  }
}

// ---- MFMA consume: 4 waves 2x2, each 64x64 via 4x4 of 16x16x32, K=64, swizzled reads ----
__device__ __forceinline__
void mfma_step(const f16* __restrict__ Ash, const f16* __restrict__ Bsh, int t, f32x4 acc[4][4])
{
  const int lane = t & 63, wid = t >> 6;
  const int wm = (wid >> 1) << 6, wn = (wid & 1) << 6;
  const int r = lane & 15;
  #pragma unroll
  for (int kh = 0; kh < 2; ++kh) {
    const int kb = ((kh << 5) | ((lane >> 4) << 3)) << 1;   // byte col
    f16x8 af[4], bf[4];
    #pragma unroll
    for (int m = 0; m < 4; ++m) af[m] = *(const f16x8*)swzp(Ash, wm + m * 16 + r, kb);
    #pragma unroll
    for (int n = 0; n < 4; ++n) bf[n] = *(const f16x8*)swzp(Bsh, wn + n * 16 + r, kb);
    #pragma unroll
    for (int m = 0; m < 4; ++m)
      #pragma unroll
      for (int n = 0; n < 4; ++n)
        acc[m][n] = __builtin_amdgcn_mfma_f32_16x16x32_f16(af[m], bf[n], acc[m][n], 0, 0, 0);
  }
}

// ---- generic GEMM body: dbuf 2-phase, BMODE: 0=gload, 1=V-transpose, 2=w3-scale ----
template<int BMODE>
__device__ __forceinline__
void mm_body(f16* A0, f16* A1, f16* B0, f16* B1,
             const f16* __restrict__ Ab, long Ars,
             const f16* __restrict__ Bb, long Brs, int K,
             const float* __restrict__ scale, int t, f32x4 acc[4][4])
{
  stage_g(A0, Ab, Ars, t);
  if (BMODE == 1) { VT v = vt_load(Bb, Brs, t); vt_write(B0, v, t); }
  else if (BMODE == 2) { f16x8 v[4]; sc_load(v, Bb, Brs, scale, t); a_write(B0, v, t); }
  else stage_g(B0, Bb, Brs, t);
  __syncthreads();
  f16 *Ac = A0, *An = A1, *Bc = B0, *Bn = B1;
  for (int k0 = 64; k0 < K; k0 += 64) {
    stage_g(An, Ab + k0, Ars, t);
    if (BMODE == 1) {
      VT v = vt_load(Bb + (long)k0 * Brs, Brs, t);
      mfma_step(Ac, Bc, t, acc);
      vt_write(Bn, v, t);
    } else if (BMODE == 2) {
      f16x8 v[4]; sc_load(v, Bb + k0, Brs, scale + k0, t);
      mfma_step(Ac, Bc, t, acc);
      a_write(Bn, v, t);
    } else {
      stage_g(Bn, Bb + k0, Brs, t);
      mfma_step(Ac, Bc, t, acc);
    }
    __syncthreads();
    f16* x = Ac; Ac = An; An = x; x = Bc; Bc = Bn; Bn = x;
  }
  mfma_step(Ac, Bc, t, acc);
}

#define DECL_TILES \
  __shared__ __align__(16) f16 A0[8192]; __shared__ __align__(16) f16 A1[8192]; \
  __shared__ __align__(16) f16 B0[8192]; __shared__ __align__(16) f16 B1[8192];

// ---- generic batched GEMM kernel ----
template<int BMODE, int RANK1, int HOUT>
__global__ __launch_bounds__(256)
void mm_kernel(const f16* __restrict__ A, long Abs, long Ars,
               const f16* __restrict__ B, long Bbs, long Brs, int K,
               const float* __restrict__ scale,
               const float* __restrict__ ql, long qlbs,
               const float* __restrict__ kl, long klbs,
               void* __restrict__ C, long Cbs, long Crs)
{
  DECL_TILES
  const int z = blockIdx.z, t = threadIdx.x;
  const int i0 = blockIdx.y << 7, j0 = blockIdx.x << 7;
  const f16* Ab = A + (long)z * Abs + (long)i0 * Ars;
  const f16* Bb = (BMODE == 1) ? (B + (long)z * Bbs + j0)
                               : (B + (long)z * Bbs + (long)j0 * Brs);
  f32x4 acc[4][4] = {};
  mm_body<BMODE>(A0, A1, B0, B1, Ab, Ars, Bb, Brs, K, scale, t, acc);
  const int lane = t & 63, wid = t >> 6;
  const int wm = (wid >> 1) << 6, wn = (wid & 1) << 6;
  const int rq = (lane >> 4) << 2, cj = lane & 15;
  #pragma unroll
  for (int m = 0; m < 4; ++m)
    #pragma unroll
    for (int q = 0; q < 4; ++q) {
      const int row = i0 + wm + m * 16 + rq + q;
      const float qv = RANK1 ? ql[(long)z * qlbs + row] : 0.f;
      #pragma unroll
      for (int n = 0; n < 4; ++n) {
        const int col = j0 + wn + n * 16 + cj;
        float v = acc[m][n][q] + qv;
        if (RANK1) v += kl[(long)z * klbs + col];
        if (HOUT) ((f16*)C)[(long)z * Cbs + (long)row * Crs + col] = (f16)v;
        else      ((float*)C)[(long)z * Cbs + (long)row * Crs + col] = v;
      }
    }
}

// ---- stage A custom kernels ----
__device__ __forceinline__ void pair_decode(int pair, int& i, int& j) {
  i = pair / 3; const int r = pair - i * 3; j = r + (r >= i ? 1 : 0);
}

__global__ __launch_bounds__(256)
void stA_logits_kernel(const f16* __restrict__ OPT, const float* __restrict__ w3,
                       const float* __restrict__ ql_all, const float* __restrict__ kl_all,
                       float* __restrict__ L)
{
  DECL_TILES
  const int z = blockIdx.z, t = threadIdx.x;
  const int pair = z >> 3, b8 = z & 7;
  int i, j; pair_decode(pair, i, j);
  const int bi = b8 * 4 + i, bj = b8 * 4 + j;
  const int i0 = blockIdx.y << 7, j0 = blockIdx.x << 7;
  f32x4 acc[4][4] = {};
  mm_body<2>(A0, A1, B0, B1, OPT + (long)bi * LLBS + (long)i0 * HDIM, HDIM,
             OPT + (long)bj * LLBS + (long)j0 * HDIM, HDIM, HDIM, w3, t, acc);
  const float* qlp = ql_all + bi * 256;
  const float* klp = kl_all + bj * 256;
  float* Cb = L + (long)z * 65536;
  const int lane = t & 63, wid = t >> 6;
  const int wm = (wid >> 1) << 6, wn = (wid & 1) << 6;
  const int rq = (lane >> 4) << 2, cj = lane & 15;
  #pragma unroll
  for (int m = 0; m < 4; ++m)
    #pragma unroll
    for (int q = 0; q < 4; ++q) {
      const int row = i0 + wm + m * 16 + rq + q;
      const float qv = qlp[row];
      #pragma unroll
      for (int n = 0; n < 4; ++n) {
        const int col = j0 + wn + n * 16 + cj;
        Cb[(long)row * 256 + col] = acc[m][n][q] + qv + klp[col];
      }
    }
}

__global__ __launch_bounds__(256)
void stA_attn_kernel(const f16* __restrict__ P, const f16* __restrict__ OPT,
                     f16* __restrict__ aBuf)
{
  DECL_TILES
  const int z = blockIdx.z, t = threadIdx.x;
  const int pair = z >> 3, b8 = z & 7;
  int i, j; pair_decode(pair, i, j);
  const int bj = b8 * 4 + j;
  const int i0 = blockIdx.y << 7, j0 = blockIdx.x << 7;
  f32x4 acc[4][4] = {};
  mm_body<1>(A0, A1, B0, B1, P + (long)z * 65536 + (long)i0 * 256, 256,
             OPT + (long)bj * LLBS + j0, HDIM, 256, nullptr, t, acc);
  const int lane = t & 63, wid = t >> 6;
  const int wm = (wid >> 1) << 6, wn = (wid & 1) << 6;
  const int rq = (lane >> 4) << 2, cj = lane & 15;
  f16* Cb = aBuf + (long)z * OPTBS;
  #pragma unroll
  for (int m = 0; m < 4; ++m)
    #pragma unroll
    for (int q = 0; q < 4; ++q) {
      const int row = i0 + wm + m * 16 + rq + q;
      #pragma unroll
      for (int n = 0; n < 4; ++n)
        Cb[(long)row * HDIM + j0 + wn + n * 16 + cj] = (f16)acc[m][n][q];
    }
}

// ---- stage A comp: fused 7-block concat-linear; A reg-staged, W via DMA; dbuf ----
__global__ __launch_bounds__(256)
void stA_comp_kernel(const f16* __restrict__ OPT, const f16* __restrict__ aBuf,
                     const f16* __restrict__ W, const float* __restrict__ bias,
                     f16* __restrict__ out)
{
  DECL_TILES
  const int Lb = blockIdx.x, t = threadIdx.x;
  const int c = Lb & 7, w = Lb >> 3;
  const int n0 = (w >> 3) << 7;
  const int g = (c << 3) | (w & 7);
  const int i0 = (g & 1) << 7;
  const int z = g >> 1;
  const int b8 = z >> 2, i = z & 3;
  const f16* cur = OPT + (long)z * LLBS;
  const f16* a0 = aBuf + (long)((i * 3 + 0) * 8 + b8) * OPTBS;
  const f16* a1 = aBuf + (long)((i * 3 + 1) * 8 + b8) * OPTBS;
  const f16* a2 = aBuf + (long)((i * 3 + 2) * 8 + b8) * OPTBS;
  const f16* Wb = W + (long)n0 * 7168;
  const int row = t >> 1, h = (t & 1) << 5;
  const long rbase = (long)(i0 + row) * HDIM + h;
  f32x4 acc[4][4] = {};
  f16x8 r0[4], r1[4];
  auto aload = [&](int k0) {
    const int blk = k0 >> 10, kk = k0 & 1023;
    const long ro = rbase + kk;
    ld4(r0, cur + ro);
    if (blk) {
      const int m = (blk - 1) >> 1;
      const f16* ap = (m == 0) ? a0 : (m == 1 ? a1 : a2);
      ld4(r1, ap + ro);
    }
  };
  auto aop = [&](int k0) {
    const int blk = k0 >> 10;
    if (blk) {
      if (blk & 1) { r0[0]*=r1[0]; r0[1]*=r1[1]; r0[2]*=r1[2]; r0[3]*=r1[3]; }
      else         { r0[0]-=r1[0]; r0[1]-=r1[1]; r0[2]-=r1[2]; r0[3]-=r1[3]; }
    }
  };
  aload(0); aop(0); a_write(A0, r0, t);
  stage_g(B0, Wb, 7168, t);
  __syncthreads();
  f16 *Ac = A0, *An = A1, *Wc = B0, *Wn = B1;
  for (int k0 = 64; k0 < 7168; k0 += 64) {
    aload(k0);
    stage_g(Wn, Wb + k0, 7168, t);
    mfma_step(Ac, Wc, t, acc);
    aop(k0);
    a_write(An, r0, t);
    __syncthreads();
    f16* x = Ac; Ac = An; An = x; x = Wc; Wc = Wn; Wn = x;
  }
  mfma_step(Ac, Wc, t, acc);
  const int lane = t & 63, wid = t >> 6;
  const int wm = (wid >> 1) << 6, wn = (wid & 1) << 6;
  const int rq = (lane >> 4) << 2, cj = lane & 15;
  f16* ob = out + (long)z * OPTBS;
  #pragma unroll
  for (int m = 0; m < 4; ++m)
    #pragma unroll
    for (int q = 0; q < 4; ++q) {
      const int r2 = i0 + wm + m * 16 + rq + q;
      #pragma unroll
      for (int n = 0; n < 4; ++n) {
        const int col = n0 + wn + n * 16 + cj;
        ob[(long)r2 * HDIM + col] = (f16)tanhf(acc[m][n][q] + bias[col]);
      }
    }
}

// ---- generic fused concat-linear (stages B, D, F) ----
struct FCSrc { const f16* s0; const f16* s1; long s0bs; long s1bs; int op; int pad; };
struct FCArgs {
  FCSrc src[4];
  int nblk; int act;            // 0=tanh, 1=relu, 2=sigmoid-lerp
  const f16* W; const float* bias;
  f16* out; long outbs;
  const f16* e0; const f16* e1; long e0bs; long e1bs;
};

__global__ __launch_bounds__(256)
void fc_mfma_kernel(FCArgs P)
{
  DECL_TILES
  const int Lb = blockIdx.x, t = threadIdx.x;
  const int c = Lb & 7, w = Lb >> 3;
  const int n0 = (w >> 3) << 7;
  const int g = (c << 3) | (w & 7);
  const int i0 = (g & 1) << 7;
  const int b = g >> 1;
  const int Ktot = P.nblk << 10;
  const f16* Wb = P.W + (long)n0 * Ktot;
  const int row = t >> 1, h = (t & 1) << 5;
  const long rbase = (long)(i0 + row) * HDIM + h;
  f32x4 acc[4][4] = {};
  f16x8 r0[4], r1[4];
  int opc = 0;
  auto aload = [&](int k0) {
    const FCSrc s = P.src[k0 >> 10];
    const int kk = k0 & 1023;
    const long ro = rbase + kk;
    opc = s.op;
    ld4(r0, s.s0 + (long)b * s.s0bs + ro);
    if (opc) ld4(r1, s.s1 + (long)b * s.s1bs + ro);
  };
  auto aop = [&]() {
    if (opc == 1)      { r0[0]*=r1[0]; r0[1]*=r1[1]; r0[2]*=r1[2]; r0[3]*=r1[3]; }
    else if (opc == 2) { r0[0]-=r1[0]; r0[1]-=r1[1]; r0[2]-=r1[2]; r0[3]-=r1[3]; }
  };
  aload(0); aop(); a_write(A0, r0, t);
  stage_g(B0, Wb, Ktot, t);
  __syncthreads();
  f16 *Ac = A0, *An = A1, *Wc = B0, *Wn = B1;
  for (int k0 = 64; k0 < Ktot; k0 += 64) {
    aload(k0);
    stage_g(Wn, Wb + k0, Ktot, t);
    mfma_step(Ac, Wc, t, acc);
    aop();
    a_write(An, r0, t);
    __syncthreads();
    f16* x = Ac; Ac = An; An = x; x = Wc; Wc = Wn; Wn = x;
  }
  mfma_step(Ac, Wc, t, acc);
  const int lane = t & 63, wid = t >> 6;
  const int wm = (wid >> 1) << 6, wn = (wid & 1) << 6;
  const int rq = (lane >> 4) << 2, cj = lane & 15;
  #pragma unroll
  for (int m = 0; m < 4; ++m)
    #pragma unroll
    for (int q = 0; q < 4; ++q) {
      const int r2 = i0 + wm + m * 16 + rq + q;
      f16* orow = P.out + (long)b * P.outbs + (long)r2 * HDIM;
      #pragma unroll
      for (int n = 0; n < 4; ++n) {
        const int col = n0 + wn + n * 16 + cj;
        float v = acc[m][n][q] + P.bias[col];
        if (P.act == 0) v = tanhf(v);
        else if (P.act == 1) v = fmaxf(v, 0.f);
        else {
          const float sg = 1.f / (1.f + __expf(-v));
          const float e = (float)P.e0[(long)b * P.e0bs + (long)r2 * HDIM + col];
          const float c2 = (float)P.e1[(long)b * P.e1bs + (long)r2 * HDIM + col];
          v = e * sg + c2 * (1.f - sg);
        }
        orow[col] = (f16)v;
      }
    }
}

// ---------------- conversions / rowdot / softmaxes / colmax ----------------
__global__ __launch_bounds__(256)
void cvt_kernel(const float* __restrict__ src, f16* __restrict__ dst, long n)
{
  long i = ((long)blockIdx.x * 256 + threadIdx.x) * 8;
  const long stride = (long)gridDim.x * 2048;
  for (; i < n; i += stride) {
    const float4 a = *(const float4*)(src + i);
    const float4 b = *(const float4*)(src + i + 4);
    *(f16x8*)(dst + i) = f16x8{(f16)a.x,(f16)a.y,(f16)a.z,(f16)a.w,
                               (f16)b.x,(f16)b.y,(f16)b.z,(f16)b.w};
  }
}

__global__ __launch_bounds__(256)
void rowdot_kernel(const f16* __restrict__ base, long bs, int R,
                   const float* __restrict__ w, float* __restrict__ out)
{
  const int row  = blockIdx.x * 4 + (threadIdx.x >> 6);
  const int lane = threadIdx.x & 63;
  const int b = row / R, r = row - b * R;
  const f16* p = base + (long)b * bs + (long)r * HDIM;
  float s = 0.f;
  #pragma unroll 4
  for (int d = lane; d < HDIM; d += 64) s += (float)p[d] * w[d];
  #pragma unroll
  for (int off = 32; off; off >>= 1) s += __shfl_down(s, off, 64);
  if (lane == 0) out[row] = s;
}

template<int CNT>
__global__ __launch_bounds__(256)
void softmax_rows_kernel(const float* __restrict__ L, f16* __restrict__ P)
{
  const int row = blockIdx.x * 4 + (threadIdx.x >> 6);
  const int lane = threadIdx.x & 63;
  const float* p = L + (long)row * (CNT * 64);
  f16* o = P + (long)row * (CNT * 64);
  float v[CNT];
  float m = -3.0e38f;
  #pragma unroll
  for (int u = 0; u < CNT; ++u) { v[u] = p[lane + (u << 6)]; m = fmaxf(m, v[u]); }
  #pragma unroll
  for (int off = 32; off; off >>= 1) m = fmaxf(m, __shfl_xor(m, off, 64));
  float s = 0.f;
  #pragma unroll
  for (int u = 0; u < CNT; ++u) { v[u] = __expf(v[u] - m); s += v[u]; }
  #pragma unroll
  for (int off = 32; off; off >>= 1) s += __shfl_xor(s, off, 64);
  const float inv = 1.f / s;
  #pragma unroll
  for (int u = 0; u < CNT; ++u) o[lane + (u << 6)] = (f16)(v[u] * inv);
}

__global__ __launch_bounds__(256)
void softmax_cols_kernel(const float* __restrict__ L, f16* __restrict__ out, int M, int N)
{
  const int b = blockIdx.y;
  const int j = blockIdx.x * 256 + threadIdx.x;
  const float* p = L + (long)b * M * N + j;
  f16* o = out + (long)b * M * N + j;
  float m = -3.0e38f;
  for (int i = 0; i < M; ++i) m = fmaxf(m, p[(long)i * N]);
  float s = 0.f;
  for (int i = 0; i < M; ++i) { const float e = __expf(p[(long)i * N] - m); o[(long)i * N] = (f16)e; s += e; }
  const float inv = 1.f / s;
  for (int i = 0; i < M; ++i) o[(long)i * N] = (f16)((float)o[(long)i * N] * inv);
}

__global__ __launch_bounds__(256)
void colmax_kernel(const f16* __restrict__ X, float* __restrict__ out)
{
  const int b = blockIdx.y;
  const int d = blockIdx.x * 256 + threadIdx.x;
  const f16* p = X + (long)b * (256 * HDIM) + d;
  float m = -3.0e38f;
  for (int r = 0; r < 256; ++r) m = fmaxf(m, (float)p[r * HDIM]);
  out[b * HDIM + d] = m;
}

extern "C" void kernel_launch(void* const* d_in, const int* in_sizes, int n_in,
                              void* d_out, int out_size, void* d_ws, size_t ws_size,
                              hipStream_t stream)
{
  (void)in_sizes; (void)n_in; (void)out_size; (void)ws_size;
  const float* last   = (const float*)d_in[4];
  const float* ow1    = (const float*)d_in[5];
  const float* ow2    = (const float*)d_in[6];
  const float* ow3    = (const float*)d_in[7];
  const float* dw1    = (const float*)d_in[8];
  const float* dw2    = (const float*)d_in[9];
  const float* dw3    = (const float*)d_in[10];
  const float* sw1    = (const float*)d_in[11];
  const float* sw2    = (const float*)d_in[12];
  const float* sw3    = (const float*)d_in[13];
  const float* comp_w = (const float*)d_in[14];
  const float* comp_b = (const float*)d_in[15];
  const float* gate_w = (const float*)d_in[16];
  const float* gate_b = (const float*)d_in[17];
  const float* attn_w = (const float*)d_in[18];
  const float* attn_b = (const float*)d_in[19];
  const float* self_w = (const float*)d_in[20];
  const float* self_b = (const float*)d_in[21];

  char* base = (char*)d_ws;
  size_t off = 0;
  auto af = [&](long n) { float* p = (float*)(base + off); off = (off + n * 4 + 15) & ~15UL; return p; };
  auto ah = [&](long n) { f16* p = (f16*)(base + off); off = (off + n * 2 + 15) & ~15UL; return p; };

  f16* lastH = ah(33554432L);
  f16* compH = ah(7340032L);
  f16* gateH = ah(2097152L);
  f16* attnH = ah(3145728L);
  f16* selfH = ah(4194304L);
  f16* aBuf  = ah(96L * OPTBS);
  f16* pA    = ah(96L * 65536);
  f16* awC   = ah(32L * 196608);
  f16* kqC   = ah(32L * 196608);
  f16* pE    = ah(32L * 65536);
  f16* co_wH = ah(32L * 65536);
  f16* buf1  = ah(32L * OPTBS);          // opt_corr, then attn_a
  f16* buf2  = ah(32L * OPTBS);          // option, then sa
  f16* buf3  = ah(32L * OPTBS);          // co, then fusion2
  f16* buf4  = ah(32L * OPTBS);          // fusion
  float* L   = af(32L * 196608);
  float* ql_all = af(8192); float* kl_all = af(8192);
  float* ql_c   = af(8192); float* kl_c   = af(24576);
  float* ql_e   = af(8192); float* kl_e   = af(8192);

  const f16* OPTH = lastH + 768 * 1024;  // (32,256,H) view, batch stride LLBS

  // ---- conversions ----
  cvt_kernel<<<2048, 256, 0, stream>>>(last,   lastH, 33554432L);
  cvt_kernel<<<512,  256, 0, stream>>>(comp_w, compH, 7340032L);
  cvt_kernel<<<256,  256, 0, stream>>>(gate_w, gateH, 2097152L);
  cvt_kernel<<<256,  256, 0, stream>>>(attn_w, attnH, 3145728L);
  cvt_kernel<<<256,  256, 0, stream>>>(self_w, selfH, 4194304L);

  // ---- stage A ----
  rowdot_kernel<<<2048, 256, 0, stream>>>(OPTH, LLBS, 256, ow1, ql_all);
  rowdot_kernel<<<2048, 256, 0, stream>>>(OPTH, LLBS, 256, ow2, kl_all);
  stA_logits_kernel<<<dim3(2, 2, 96), 256, 0, stream>>>(OPTH, ow3, ql_all, kl_all, L);
  softmax_rows_kernel<4><<<(96 * 256) / 4, 256, 0, stream>>>(L, pA);
  stA_attn_kernel<<<dim3(8, 2, 96), 256, 0, stream>>>(pA, OPTH, aBuf);
  stA_comp_kernel<<<512, 256, 0, stream>>>(OPTH, aBuf, compH, comp_b, buf1);

  // ---- stage B: gate ----
  {
    FCArgs P = {};
    P.src[0] = {OPTH, nullptr, LLBS,  0, 0, 0};
    P.src[1] = {buf1, nullptr, OPTBS, 0, 0, 0};
    P.nblk = 2; P.act = 2; P.W = gateH; P.bias = gate_b;
    P.e0 = OPTH; P.e0bs = LLBS; P.e1 = buf1; P.e1bs = OPTBS;
    P.out = buf2; P.outbs = OPTBS;
    fc_mfma_kernel<<<512, 256, 0, stream>>>(P);
  }

  // ---- stage C: doc attention ----
  rowdot_kernel<<<2048, 256, 0, stream>>>(buf2, OPTBS, 256, dw1, ql_c);
  rowdot_kernel<<<6144, 256, 0, stream>>>(lastH, LLBS, 768, dw2, kl_c);
  mm_kernel<2, 1, 0><<<dim3(6, 2, 32), 256, 0, stream>>>(buf2, OPTBS, HDIM, lastH, LLBS, HDIM, HDIM,
                                                         dw3, ql_c, 256, kl_c, 768, L, 196608, 768);
  softmax_cols_kernel<<<dim3(3, 32), 256, 0, stream>>>(L, kqC, 256, 768);
  softmax_rows_kernel<12><<<8192 / 4, 256, 0, stream>>>(L, awC);
  mm_kernel<1, 0, 1><<<dim3(8, 2, 32), 256, 0, stream>>>(awC, 196608, 768, lastH, LLBS, HDIM, 768,
                                                         nullptr, nullptr, 0, nullptr, 0, buf1, OPTBS, HDIM);
  mm_kernel<0, 0, 1><<<dim3(2, 2, 32), 256, 0, stream>>>(awC, 196608, 768, kqC, 196608, 768, 768,
                                                         nullptr, nullptr, 0, nullptr, 0, co_wH, 65536, 256);
  mm_kernel<1, 0, 1><<<dim3(8, 2, 32), 256, 0, stream>>>(co_wH, 65536, 256, buf2, OPTBS, HDIM, 256,
                                                         nullptr, nullptr, 0, nullptr, 0, buf3, OPTBS, HDIM);

  // ---- stage D: fusion ----
  {
    FCArgs P = {};
    P.src[0] = {buf2, nullptr, OPTBS, 0, 0, 0};
    P.src[1] = {buf1, nullptr, OPTBS, 0, 0, 0};
    P.src[2] = {buf3, nullptr, OPTBS, 0, 0, 0};
    P.nblk = 3; P.act = 1; P.W = attnH; P.bias = attn_b;
    P.out = buf4; P.outbs = OPTBS;
    fc_mfma_kernel<<<512, 256, 0, stream>>>(P);
  }

  // ---- stage E: self-attention ----
  rowdot_kernel<<<2048, 256, 0, stream>>>(buf4, OPTBS, 256, sw1, ql_e);
  rowdot_kernel<<<2048, 256, 0, stream>>>(buf4, OPTBS, 256, sw2, kl_e);
  mm_kernel<2, 1, 0><<<dim3(2, 2, 32), 256, 0, stream>>>(buf4, OPTBS, HDIM, buf4, OPTBS, HDIM, HDIM,
                                                         sw3, ql_e, 256, kl_e, 256, L, 65536, 256);
  softmax_rows_kernel<4><<<8192 / 4, 256, 0, stream>>>(L, pE);
  mm_kernel<1, 0, 1><<<dim3(8, 2, 32), 256, 0, stream>>>(pE, 65536, 256, buf4, OPTBS, HDIM, 256,
                                                         nullptr, nullptr, 0, nullptr, 0, buf2, OPTBS, HDIM);

  // ---- stage F: fusion2 ----
  {
    FCArgs P = {};
    P.src[0] = {buf4, nullptr, OPTBS, 0, 0, 0};
    P.src[1] = {buf2, nullptr, OPTBS, 0, 0, 0};
    P.src[2] = {buf4, buf2, OPTBS, OPTBS, 1, 0};
    P.src[3] = {buf4, buf2, OPTBS, OPTBS, 2, 0};
    P.nblk = 4; P.act = 1; P.W = selfH; P.bias = self_b;
    P.out = buf3; P.outbs = OPTBS;
    fc_mfma_kernel<<<512, 256, 0, stream>>>(P);
  }

  // ---- stage G ----
  colmax_kernel<<<dim3(4, 32), 256, 0, stream>>>(buf3, (float*)d_out);
}